// Round 7
// baseline (328.931 us; speedup 1.0000x reference)
//
#include <hip/hip_runtime.h>
#include <hip/hip_fp16.h>

#define NB 512
#define DD 128
#define SS 50
#define TT 32
#define LL 64
#define CLIPN 50
#define NFRIENDS 10000
#define NTHREADS 768
#define NWAVES 12
#define NGROUP 6
#define PAD1 50001              // word table rows (PAD+1)
#define WELEMS (PAD1 * DD)      // 6,400,128 (divisible by 16)

typedef unsigned short u16;
typedef unsigned int u32;

__device__ __forceinline__ float bf2f(u32 u) {
    union { u32 i; float f; } c; c.i = u << 16; return c.f;
}
__device__ __forceinline__ u16 f2bf(float f) {
    union { float f; u32 i; } c; c.f = f;
    u32 x = c.i;
    return (u16)((x + 0x7fffu + ((x >> 16) & 1u)) >> 16);
}
__device__ __forceinline__ float sigf(float x) { return 1.f / (1.f + expf(-x)); }

// ---- e5m2 <-> half2 (pure byte shifts; e5m2 is fp16's top byte) -----------
__device__ __forceinline__ __half2 u2h2(u32 u) {
    union { u32 u; __half2 h; } c; c.u = u; return c.h;
}
__device__ __forceinline__ __half2 e5m2lo(u32 w) {     // dims (0,1) of the word
    return u2h2(((w & 0x000000ffu) << 8) | ((w & 0x0000ff00u) << 16));
}
__device__ __forceinline__ __half2 e5m2hi(u32 w) {     // dims (2,3)
    return u2h2(((w >> 8) & 0x0000ff00u) | (w & 0xff000000u));
}
__device__ __forceinline__ void e5m2_dec4(u32 w, float* o) {
    float2 a = __half22float2(e5m2lo(w)), b = __half22float2(e5m2hi(w));
    o[0] = a.x; o[1] = a.y; o[2] = b.x; o[3] = b.y;
}
__device__ __forceinline__ u32 e5m2_byte(float x) {
    u16 h = __half_as_ushort(__float2half(x));          // f32 -> f16 RNE
    u16 r = (u16)(h + 0x7Fu + ((h >> 8) & 1u));         // RNE to top byte
    return (r >> 8) & 0xffu;
}
__device__ __forceinline__ u32 e5m2_enc4(const float* v) {
    return e5m2_byte(v[0]) | (e5m2_byte(v[1]) << 8) |
           (e5m2_byte(v[2]) << 16) | (e5m2_byte(v[3]) << 24);
}

// ---- dtype-generic scalar load/store (non-word-table tensors) -------------
template <bool BF16> struct LD;
template <> struct LD<true> {
    static __device__ __forceinline__ float one(const void* p, long i) {
        return bf2f(((const u16*)p)[i]);
    }
    static __device__ __forceinline__ void st(void* p, long i, float v) {
        ((u16*)p)[i] = f2bf(v);
    }
};
template <> struct LD<false> {
    static __device__ __forceinline__ float one(const void* p, long i) {
        return ((const float*)p)[i];
    }
    static __device__ __forceinline__ void st(void* p, long i, float v) {
        ((float*)p)[i] = v;
    }
};

// ---- word-table accessors for fallback modes: WM 0=fp32, 1=bf16 -----------
template <int WM> struct WT;
template <> struct WT<0> {
    static __device__ __forceinline__ void sixteen(const void* p, long i, float* o) {
        const float* s = (const float*)p + i;
        #pragma unroll
        for (int j = 0; j < 4; ++j) {
            float4 v = *(const float4*)(s + 4 * j);
            o[4*j] = v.x; o[4*j+1] = v.y; o[4*j+2] = v.z; o[4*j+3] = v.w;
        }
    }
    static __device__ __forceinline__ void four(const void* p, long i, float* o) {
        float4 v = *(const float4*)((const float*)p + i);
        o[0] = v.x; o[1] = v.y; o[2] = v.z; o[3] = v.w;
    }
};
template <> struct WT<1> {
    static __device__ __forceinline__ void sixteen(const void* p, long i, float* o) {
        const u16* s = (const u16*)p + i;
        #pragma unroll
        for (int j = 0; j < 2; ++j) {
            uint4 v = *(const uint4*)(s + 8 * j);
            float* q = o + 8 * j;
            q[0] = bf2f(v.x & 0xffffu); q[1] = bf2f(v.x >> 16);
            q[2] = bf2f(v.y & 0xffffu); q[3] = bf2f(v.y >> 16);
            q[4] = bf2f(v.z & 0xffffu); q[5] = bf2f(v.z >> 16);
            q[6] = bf2f(v.w & 0xffffu); q[7] = bf2f(v.w >> 16);
        }
    }
    static __device__ __forceinline__ void four(const void* p, long i, float* o) {
        uint2 v = *(const uint2*)((const u16*)p + i);
        o[0] = bf2f(v.x & 0xffffu); o[1] = bf2f(v.x >> 16);
        o[2] = bf2f(v.y & 0xffffu); o[3] = bf2f(v.y >> 16);
    }
};

// ---- dtype sniffing -------------------------------------------------------
__global__ void sniff_dtype(const void* __restrict__ emb_word, int* __restrict__ flag) {
    const u16* p = (const u16*)emb_word;
    int lane = (int)threadIdx.x;
    int bad = 0;
    #pragma unroll
    for (int j = 0; j < 8; ++j) {
        unsigned e = (p[lane * 8 + j] >> 7) & 0xffu;
        bad += (e >= 127u);
    }
    #pragma unroll
    for (int off = 1; off < 64; off <<= 1) bad += __shfl_xor(bad, off, 64);
    if (lane == 0) flag[0] = (bad <= 16) ? 1 : 0;   // 1 = bf16, 0 = fp32
}

// ---- word table -> e5m2 in workspace --------------------------------------
__global__ void convert_words(const void* __restrict__ src, u32* __restrict__ dst,
                              const int* __restrict__ flag) {
    long idx = (long)blockIdx.x * 256 + threadIdx.x;
    long i = idx * 16;
    if (i >= WELEMS) return;
    float v[16];
    if (flag[0] == 0) {                       // fp32 source
        const float* s = (const float*)src + i;
        #pragma unroll
        for (int j = 0; j < 4; ++j) {
            float4 q = *(const float4*)(s + 4 * j);
            v[4*j] = q.x; v[4*j+1] = q.y; v[4*j+2] = q.z; v[4*j+3] = q.w;
        }
    } else {                                  // bf16 source
        WT<1>::sixteen(src, i, v);
    }
    uint4 o;
    o.x = e5m2_enc4(v); o.y = e5m2_enc4(v + 4);
    o.z = e5m2_enc4(v + 8); o.w = e5m2_enc4(v + 12);
    *(uint4*)(dst + idx * 4) = o;
}

// BF16 = native input dtype; WM = word-table storage (0 fp32, 1 bf16, 2 e5m2)
template <bool BF16, int WM>
__global__ __launch_bounds__(NTHREADS, 6)   // 6 waves/EU -> VGPR cap 85
void nrs_fused(const int* __restrict__ user_idx,
               const int* __restrict__ item_idx,
               const void* __restrict__ wtab,
               const void* __restrict__ emb_item,
               const void* __restrict__ emb_user,
               const void* __restrict__ W_mem, const void* __restrict__ b_mem,
               const void* __restrict__ w_word, const void* __restrict__ b_word,
               const void* __restrict__ w_sent, const void* __restrict__ b_sent,
               const void* __restrict__ W_tr, const void* __restrict__ b_tr,
               const void* __restrict__ W1, const void* __restrict__ b1,
               const void* __restrict__ W2, const void* __restrict__ b2,
               const void* __restrict__ W3, const void* __restrict__ b3,
               const void* __restrict__ w_aff, const void* __restrict__ b_aff,
               const int* __restrict__ uti, const int* __restrict__ ufi,
               void* __restrict__ out, const int* __restrict__ flag)
{
    if (flag[0] != (BF16 ? 1 : 0)) return;   // uniform early exit

    __shared__ float s_mem[DD];
    __shared__ __align__(16) u32 s_memh[DD / 2];   // mem as packed half2
    __shared__ float s_item[LL];
    __shared__ float s_sent[SS * DD];
    __shared__ float s_part[NGROUP * DD];
    __shared__ int   s_uti[SS * TT];
    __shared__ float s_sw[SS];
    __shared__ float s_swf[SS];
    __shared__ float s_q[LL];
    __shared__ float s_ept[LL];
    __shared__ float s_uemb[LL];
    __shared__ int   s_fidx[CLIPN];
    __shared__ float s_g[CLIPN];
    __shared__ float s_a1[32];
    __shared__ float s_a2[16];
    __shared__ float s_alpha[2];
    __shared__ float s_fnum;

    const int b = blockIdx.x;
    const int tid = (int)threadIdx.x;
    const int lane = tid & 63;
    const int wave = tid >> 6;

    const int u = user_idx[b];
    const int it = item_idx[b];
    const long utb = (long)u * (SS * TT);

    if (tid < LL) s_item[tid] = LD<BF16>::one(emb_item, (long)it * LL + tid);
    __syncthreads();

    // mem = item_emb @ W_mem + b_mem (tid<128) | stage tweet indices (all)
    for (int i = tid; i < SS * TT; i += NTHREADS) s_uti[i] = uti[utb + i];
    if (tid < DD) {
        float acc = LD<BF16>::one(b_mem, tid);
        #pragma unroll 8
        for (int l = 0; l < LL; ++l)
            acc += s_item[l] * LD<BF16>::one(W_mem, l * DD + tid);
        s_mem[tid] = acc;
    }
    __syncthreads();
    if (tid < DD / 2) {
        union { u32 u; __half2 h; } c;
        c.h = __floats2half2_rn(s_mem[2 * tid], s_mem[2 * tid + 1]);
        s_memh[tid] = c.u;
    }
    __syncthreads();

    const float bw = LD<BF16>::one(b_word, 0);
    const float bs = LD<BF16>::one(b_sent, 0);
    const int dq = lane & 31;        // dim quad for weighted pass
    const int th = lane >> 5;        // t half for weighted pass
    float ww4[4];
    #pragma unroll
    for (int k = 0; k < 4; ++k) ww4[k] = LD<BF16>::one(w_word, 4 * dq + k);
    const float ws0 = LD<BF16>::one(w_sent, lane);
    const float ws1 = LD<BF16>::one(w_sent, lane + 64);
    const __half2 z2 = __float2half2_rn(0.f);

    for (int hoop = 0; hoop < 2; ++hoop) {
        for (int s = wave; s < SS; s += NWAVES) {
            // ---- score pass: lane = 2t+h; 64 dims per lane ----
            const int t = lane >> 1, h = lane & 1;
            const int row = s_uti[s * TT + t];
            float acc;
            if constexpr (WM == 2) {
                const unsigned char* rp = (const unsigned char*)wtab + (long)row * DD + h * 64;
                __half2 ah0 = z2, ah1 = z2, ah2 = z2, ah3 = z2;
                #pragma unroll
                for (int j = 0; j < 4; ++j) {
                    uint4 v = *(const uint4*)(rp + 16 * j);
                    const u32* mh = &s_memh[h * 32 + 8 * j];
                    uint4 m0 = *(const uint4*)(mh);
                    uint4 m1 = *(const uint4*)(mh + 4);
                    ah0 = __hfma2(e5m2lo(v.x), u2h2(m0.x), ah0);
                    ah1 = __hfma2(e5m2hi(v.x), u2h2(m0.y), ah1);
                    ah2 = __hfma2(e5m2lo(v.y), u2h2(m0.z), ah2);
                    ah3 = __hfma2(e5m2hi(v.y), u2h2(m0.w), ah3);
                    ah0 = __hfma2(e5m2lo(v.z), u2h2(m1.x), ah0);
                    ah1 = __hfma2(e5m2hi(v.z), u2h2(m1.y), ah1);
                    ah2 = __hfma2(e5m2lo(v.w), u2h2(m1.z), ah2);
                    ah3 = __hfma2(e5m2hi(v.w), u2h2(m1.w), ah3);
                }
                __half2 ah = __hadd2(__hadd2(ah0, ah1), __hadd2(ah2, ah3));
                acc = __low2float(ah) + __high2float(ah);
            } else {
                const long base = (long)row * DD + h * 64;
                acc = 0.f;
                #pragma unroll
                for (int j = 0; j < 4; ++j) {
                    float v16[16];
                    WT<WM>::sixteen(wtab, base + 16 * j, v16);
                    const float* mp = &s_mem[h * 64 + 16 * j];
                    #pragma unroll
                    for (int k = 0; k < 16; ++k) acc += v16[k] * mp[k];
                }
            }
            acc += __shfl_xor(acc, 1, 64);   // score[t] in lanes 2t, 2t+1

            float mx = acc;
            #pragma unroll
            for (int off = 1; off < 64; off <<= 1) mx = fmaxf(mx, __shfl_xor(mx, off, 64));
            float e = expf(acc - mx);
            float sm = e;
            #pragma unroll
            for (int off = 1; off < 64; off <<= 1) sm += __shfl_xor(sm, off, 64);
            float wwt = 2.f * e / sm;        // ww[t] (duplicated per pair)

            // ---- weighted-sum: lane handles dims [4dq,4dq+4), t in its half ----
            float a0, a1, a2, a3;
            if constexpr (WM == 2) {
                __half2 p01 = z2, p23 = z2;
                #pragma unroll 4
                for (int i2 = 0; i2 < 16; ++i2) {
                    int t2 = th * 16 + i2;
                    float wv = __shfl(wwt, 2 * t2, 64);
                    int r2 = s_uti[s * TT + t2];
                    u32 w = *(const u32*)((const unsigned char*)wtab + (long)r2 * DD + 4 * dq);
                    __half2 wvh = __float2half2_rn(wv);
                    p01 = __hfma2(wvh, e5m2lo(w), p01);
                    p23 = __hfma2(wvh, e5m2hi(w), p23);
                }
                a0 = __low2float(p01); a1 = __high2float(p01);
                a2 = __low2float(p23); a3 = __high2float(p23);
            } else {
                a0 = a1 = a2 = a3 = 0.f;
                #pragma unroll 4
                for (int i2 = 0; i2 < 16; ++i2) {
                    int t2 = th * 16 + i2;
                    float wv = __shfl(wwt, 2 * t2, 64);
                    int r2 = s_uti[s * TT + t2];
                    float v4[4];
                    WT<WM>::four(wtab, (long)r2 * DD + 4 * dq, v4);
                    a0 += wv * v4[0]; a1 += wv * v4[1];
                    a2 += wv * v4[2]; a3 += wv * v4[3];
                }
            }
            a0 += __shfl_xor(a0, 32, 64);
            a1 += __shfl_xor(a1, 32, 64);
            a2 += __shfl_xor(a2, 32, 64);
            a3 += __shfl_xor(a3, 32, 64);
            if (th == 0)
                *(float4*)&s_sent[s * DD + 4 * dq] = make_float4(a0, a1, a2, a3);

            // sw[s] = sentence . w_word + b_word (each dim counted twice)
            float p = a0 * ww4[0] + a1 * ww4[1] + a2 * ww4[2] + a3 * ww4[3];
            #pragma unroll
            for (int off = 1; off < 64; off <<= 1) p += __shfl_xor(p, off, 64);
            if (lane == 0) s_sw[s] = 0.5f * p + bw;
        }
        __syncthreads();

        // sentence-level softmax (wave 0)
        if (wave == 0) {
            float p = s_mem[lane] * ws0 + s_mem[lane + 64] * ws1;
            #pragma unroll
            for (int off = 1; off < 64; off <<= 1) p += __shfl_xor(p, off, 64);
            float iw = p + bs;
            float v = (lane < SS) ? tanhf(s_sw[lane] + iw) : -2.f;  // tanh in [-1,1]
            float mx = v;
            #pragma unroll
            for (int off = 1; off < 64; off <<= 1) mx = fmaxf(mx, __shfl_xor(mx, off, 64));
            float e = (lane < SS) ? expf(v - mx) : 0.f;
            float sm = e;
            #pragma unroll
            for (int off = 1; off < 64; off <<= 1) sm += __shfl_xor(sm, off, 64);
            if (lane < SS) s_swf[lane] = e / sm;
        }
        __syncthreads();

        // mem += sum_s swf[s]*sentence[s] : 6-group parallel partial sums
        {
            int g = tid >> 7;           // 0..5
            int d = tid & (DD - 1);
            float acc = 0.f;
            for (int s2 = g; s2 < SS; s2 += NGROUP)
                acc += s_swf[s2] * s_sent[s2 * DD + d];
            s_part[g * DD + d] = acc;
        }
        __syncthreads();
        if (tid < DD / 2) {
            float a0 = s_mem[2 * tid], a1 = s_mem[2 * tid + 1];
            #pragma unroll
            for (int g = 0; g < NGROUP; ++g) {
                a0 += s_part[g * DD + 2 * tid];
                a1 += s_part[g * DD + 2 * tid + 1];
            }
            s_mem[2 * tid] = a0; s_mem[2 * tid + 1] = a1;
            union { u32 u; __half2 h; } c;
            c.h = __floats2half2_rn(a0, a1);
            s_memh[tid] = c.u;
        }
        __syncthreads();
    }

    // ---------------- tail ----------------
    if (tid < LL) {
        float acc = LD<BF16>::one(b_tr, tid);
        for (int d = 0; d < DD; ++d)
            acc += s_mem[d] * LD<BF16>::one(W_tr, d * LL + tid);
        s_ept[tid] = acc;
    } else if (tid < 128) {
        int l = tid - 64;
        s_q[l] = s_item[l] * LD<BF16>::one(w_aff, l);
    } else if (tid < 128 + CLIPN) {
        s_fidx[tid - 128] = ufi[(long)u * CLIPN + (tid - 128)];
    } else if (tid >= 192 && tid < 224) {
        int j = tid - 192;
        float acc = LD<BF16>::one(b1, j);
        for (int l = 0; l < LL; ++l)
            acc += s_item[l] * LD<BF16>::one(W1, l * 32 + j);
        s_a1[j] = sigf(acc);
    }
    __syncthreads();

    const float baff = LD<BF16>::one(b_aff, 0);
    if (tid < CLIPN) {
        long fb = (long)s_fidx[tid] * LL;
        float acc = 0.f;
        for (int l = 0; l < LL; ++l) acc += LD<BF16>::one(emb_user, fb + l) * s_q[l];
        float g = sigf(acc + baff);
        s_g[tid] = g;
        LD<BF16>::st(out, NB + (long)b * CLIPN + tid, g);
    } else if (tid >= 64 && tid < 80) {
        int j = tid - 64;
        float acc = LD<BF16>::one(b2, j);
        for (int k = 0; k < 32; ++k) acc += s_a1[k] * LD<BF16>::one(W2, k * 16 + j);
        s_a2[j] = sigf(acc);
    } else if (tid == 80) {
        int cnt = 0;
        for (int c = 0; c < CLIPN; ++c) cnt += (s_fidx[c] == NFRIENDS);
        s_fnum = (float)(CLIPN - cnt);
    }
    __syncthreads();

    if (tid >= 64 && tid < 128) {
        int l = tid - 64;
        float acc = 0.f;
        for (int c = 0; c < CLIPN; ++c)
            acc += s_g[c] * LD<BF16>::one(emb_user, (long)s_fidx[c] * LL + l);
        s_uemb[l] = acc;
    } else if (tid < 2) {
        float acc = LD<BF16>::one(b3, tid);
        for (int k = 0; k < 16; ++k) acc += s_a2[k] * LD<BF16>::one(W3, k * 2 + tid);
        s_alpha[tid] = sigf(acc);
    }
    __syncthreads();

    if (wave == 0) {
        float vec = s_alpha[0] * s_ept[lane] + s_alpha[1] * (s_uemb[lane] / s_fnum);
        float p = vec * s_q[lane];
        #pragma unroll
        for (int off = 1; off < 64; off <<= 1) p += __shfl_xor(p, off, 64);
        if (lane == 0) LD<BF16>::st(out, b, sigf(p + baff));
    }
}

extern "C" void kernel_launch(void* const* d_in, const int* in_sizes, int n_in,
                              void* d_out, int out_size, void* d_ws, size_t ws_size,
                              hipStream_t stream) {
    (void)in_sizes; (void)n_in; (void)out_size;
    int* flag = (int*)d_ws;
    u32* wbuf = (u32*)((char*)d_ws + 64);
    const size_t need = 64 + (size_t)WELEMS;          // ~6.1 MiB of e5m2 bytes
    const bool ws_ok = ws_size >= need;

    sniff_dtype<<<1, 64, 0, stream>>>(d_in[2], flag);

    #define ARGS(WORDP)                                                        \
        (const int*)d_in[0], (const int*)d_in[1],                              \
        WORDP, d_in[3], d_in[4],                                               \
        d_in[5], d_in[6], d_in[7], d_in[8], d_in[9], d_in[10],                 \
        d_in[11], d_in[12], d_in[13], d_in[14], d_in[15], d_in[16],            \
        d_in[17], d_in[18], d_in[19], d_in[20],                                \
        (const int*)d_in[21], (const int*)d_in[22],                            \
        d_out, (const int*)flag

    if (ws_ok) {
        const long nthr = (WELEMS + 15) / 16;
        convert_words<<<(int)((nthr + 255) / 256), 256, 0, stream>>>(
            d_in[2], wbuf, flag);
        nrs_fused<true, 2><<<NB, NTHREADS, 0, stream>>>(ARGS((const void*)wbuf));
        nrs_fused<false, 2><<<NB, NTHREADS, 0, stream>>>(ARGS((const void*)wbuf));
    } else {
        nrs_fused<true, 1><<<NB, NTHREADS, 0, stream>>>(ARGS(d_in[2]));
        nrs_fused<false, 0><<<NB, NTHREADS, 0, stream>>>(ARGS(d_in[2]));
    }
    #undef ARGS
}

// Round 8
// 320.102 us; speedup vs baseline: 1.0276x; 1.0276x over previous
//
#include <hip/hip_runtime.h>
#include <hip/hip_fp16.h>

#define NB 512
#define DD 128
#define SS 50
#define TT 32
#define LL 64
#define CLIPN 50
#define NFRIENDS 10000
#define NTHREADS 768
#define NWAVES 12
#define NGROUP 6
#define PAD1 50001              // word table rows (PAD+1)
#define WELEMS (PAD1 * DD)      // 6,400,128 (divisible by 16)

typedef unsigned short u16;
typedef unsigned int u32;

__device__ __forceinline__ float bf2f(u32 u) {
    union { u32 i; float f; } c; c.i = u << 16; return c.f;
}
__device__ __forceinline__ u16 f2bf(float f) {
    union { float f; u32 i; } c; c.f = f;
    u32 x = c.i;
    return (u16)((x + 0x7fffu + ((x >> 16) & 1u)) >> 16);
}
__device__ __forceinline__ float sigf(float x) { return 1.f / (1.f + expf(-x)); }

// ---- e5m2 <-> half2 (pure byte shifts; e5m2 is fp16's top byte) -----------
__device__ __forceinline__ __half2 u2h2(u32 u) {
    union { u32 u; __half2 h; } c; c.u = u; return c.h;
}
__device__ __forceinline__ u32 h22u(__half2 h) {
    union { __half2 h; u32 u; } c; c.h = h; return c.u;
}
__device__ __forceinline__ __half2 e5m2lo(u32 w) {     // dims (0,1) of the word
    return u2h2(((w & 0x000000ffu) << 8) | ((w & 0x0000ff00u) << 16));
}
__device__ __forceinline__ __half2 e5m2hi(u32 w) {     // dims (2,3)
    return u2h2(((w >> 8) & 0x0000ff00u) | (w & 0xff000000u));
}
__device__ __forceinline__ u32 e5m2_byte(float x) {
    u16 h = __half_as_ushort(__float2half(x));          // f32 -> f16 RNE
    u16 r = (u16)(h + 0x7Fu + ((h >> 8) & 1u));         // RNE to top byte
    return (r >> 8) & 0xffu;
}
__device__ __forceinline__ u32 e5m2_enc4(const float* v) {
    return e5m2_byte(v[0]) | (e5m2_byte(v[1]) << 8) |
           (e5m2_byte(v[2]) << 16) | (e5m2_byte(v[3]) << 24);
}

// ---- dtype-generic scalar load/store (non-word-table tensors) -------------
template <bool BF16> struct LD;
template <> struct LD<true> {
    static __device__ __forceinline__ float one(const void* p, long i) {
        return bf2f(((const u16*)p)[i]);
    }
    static __device__ __forceinline__ void st(void* p, long i, float v) {
        ((u16*)p)[i] = f2bf(v);
    }
};
template <> struct LD<false> {
    static __device__ __forceinline__ float one(const void* p, long i) {
        return ((const float*)p)[i];
    }
    static __device__ __forceinline__ void st(void* p, long i, float v) {
        ((float*)p)[i] = v;
    }
};

// ---- word-table accessors for fallback modes: WM 0=fp32, 1=bf16 -----------
template <int WM> struct WT;
template <> struct WT<0> {
    static __device__ __forceinline__ void sixteen(const void* p, long i, float* o) {
        const float* s = (const float*)p + i;
        #pragma unroll
        for (int j = 0; j < 4; ++j) {
            float4 v = *(const float4*)(s + 4 * j);
            o[4*j] = v.x; o[4*j+1] = v.y; o[4*j+2] = v.z; o[4*j+3] = v.w;
        }
    }
    static __device__ __forceinline__ void four(const void* p, long i, float* o) {
        float4 v = *(const float4*)((const float*)p + i);
        o[0] = v.x; o[1] = v.y; o[2] = v.z; o[3] = v.w;
    }
};
template <> struct WT<1> {
    static __device__ __forceinline__ void sixteen(const void* p, long i, float* o) {
        const u16* s = (const u16*)p + i;
        #pragma unroll
        for (int j = 0; j < 2; ++j) {
            uint4 v = *(const uint4*)(s + 8 * j);
            float* q = o + 8 * j;
            q[0] = bf2f(v.x & 0xffffu); q[1] = bf2f(v.x >> 16);
            q[2] = bf2f(v.y & 0xffffu); q[3] = bf2f(v.y >> 16);
            q[4] = bf2f(v.z & 0xffffu); q[5] = bf2f(v.z >> 16);
            q[6] = bf2f(v.w & 0xffffu); q[7] = bf2f(v.w >> 16);
        }
    }
    static __device__ __forceinline__ void four(const void* p, long i, float* o) {
        uint2 v = *(const uint2*)((const u16*)p + i);
        o[0] = bf2f(v.x & 0xffffu); o[1] = bf2f(v.x >> 16);
        o[2] = bf2f(v.y & 0xffffu); o[3] = bf2f(v.y >> 16);
    }
};

// ---- dtype sniffing -------------------------------------------------------
__global__ void sniff_dtype(const void* __restrict__ emb_word, int* __restrict__ flag) {
    const u16* p = (const u16*)emb_word;
    int lane = (int)threadIdx.x;
    int bad = 0;
    #pragma unroll
    for (int j = 0; j < 8; ++j) {
        unsigned e = (p[lane * 8 + j] >> 7) & 0xffu;
        bad += (e >= 127u);
    }
    #pragma unroll
    for (int off = 1; off < 64; off <<= 1) bad += __shfl_xor(bad, off, 64);
    if (lane == 0) flag[0] = (bad <= 16) ? 1 : 0;   // 1 = bf16, 0 = fp32
}

// ---- word table -> e5m2 in workspace --------------------------------------
__global__ void convert_words(const void* __restrict__ src, u32* __restrict__ dst,
                              const int* __restrict__ flag) {
    long idx = (long)blockIdx.x * 256 + threadIdx.x;
    long i = idx * 16;
    if (i >= WELEMS) return;
    float v[16];
    if (flag[0] == 0) {                       // fp32 source
        const float* s = (const float*)src + i;
        #pragma unroll
        for (int j = 0; j < 4; ++j) {
            float4 q = *(const float4*)(s + 4 * j);
            v[4*j] = q.x; v[4*j+1] = q.y; v[4*j+2] = q.z; v[4*j+3] = q.w;
        }
    } else {                                  // bf16 source
        WT<1>::sixteen(src, i, v);
    }
    uint4 o;
    o.x = e5m2_enc4(v); o.y = e5m2_enc4(v + 4);
    o.z = e5m2_enc4(v + 8); o.w = e5m2_enc4(v + 12);
    *(uint4*)(dst + idx * 4) = o;
}

// BF16 = native input dtype; WM = word-table storage (0 fp32, 1 bf16, 2 e5m2)
template <bool BF16, int WM>
__global__ __launch_bounds__(NTHREADS, 4)   // cap 128 VGPR — natural ~64, NO spills
void nrs_fused(const int* __restrict__ user_idx,
               const int* __restrict__ item_idx,
               const void* __restrict__ wtab,
               const void* __restrict__ emb_item,
               const void* __restrict__ emb_user,
               const void* __restrict__ W_mem, const void* __restrict__ b_mem,
               const void* __restrict__ w_word, const void* __restrict__ b_word,
               const void* __restrict__ w_sent, const void* __restrict__ b_sent,
               const void* __restrict__ W_tr, const void* __restrict__ b_tr,
               const void* __restrict__ W1, const void* __restrict__ b1,
               const void* __restrict__ W2, const void* __restrict__ b2,
               const void* __restrict__ W3, const void* __restrict__ b3,
               const void* __restrict__ w_aff, const void* __restrict__ b_aff,
               const int* __restrict__ uti, const int* __restrict__ ufi,
               void* __restrict__ out, const int* __restrict__ flag)
{
    if (flag[0] != (BF16 ? 1 : 0)) return;   // uniform early exit

    __shared__ float s_mem[DD];
    __shared__ __align__(16) u32 s_memh[DD / 2];   // mem as packed half2
    __shared__ float s_item[LL];
    __shared__ float s_sent[SS * DD];
    __shared__ float s_part[NGROUP * DD];
    __shared__ int   s_uti[SS * TT];
    __shared__ float s_sw[SS];
    __shared__ float s_swf[SS];
    __shared__ float s_q[LL];
    __shared__ float s_ept[LL];
    __shared__ float s_uemb[LL];
    __shared__ int   s_fidx[CLIPN];
    __shared__ float s_g[CLIPN];
    __shared__ float s_a1[32];
    __shared__ float s_a2[16];
    __shared__ float s_alpha[2];
    __shared__ float s_fnum;

    const int b = blockIdx.x;
    const int tid = (int)threadIdx.x;
    const int lane = tid & 63;
    const int wave = tid >> 6;

    const int u = user_idx[b];
    const int it = item_idx[b];
    const long utb = (long)u * (SS * TT);

    if (tid < LL) s_item[tid] = LD<BF16>::one(emb_item, (long)it * LL + tid);
    __syncthreads();

    // mem = item_emb @ W_mem + b_mem (tid<128) | stage tweet indices (all)
    for (int i = tid; i < SS * TT; i += NTHREADS) s_uti[i] = uti[utb + i];
    if (tid < DD) {
        float acc = LD<BF16>::one(b_mem, tid);
        #pragma unroll 8
        for (int l = 0; l < LL; ++l)
            acc += s_item[l] * LD<BF16>::one(W_mem, l * DD + tid);
        s_mem[tid] = acc;
    }
    __syncthreads();
    if (tid < DD / 2) {
        s_memh[tid] = h22u(__floats2half2_rn(s_mem[2 * tid], s_mem[2 * tid + 1]));
    }
    __syncthreads();

    const float bw = LD<BF16>::one(b_word, 0);
    const float bs = LD<BF16>::one(b_sent, 0);
    const int dq = lane & 31;        // dim quad for weighted pass
    const int th = lane >> 5;        // t half for weighted pass
    float ww4[4];
    #pragma unroll
    for (int k = 0; k < 4; ++k) ww4[k] = LD<BF16>::one(w_word, 4 * dq + k);
    const float ws0 = LD<BF16>::one(w_sent, lane);
    const float ws1 = LD<BF16>::one(w_sent, lane + 64);
    const __half2 z2 = __float2half2_rn(0.f);

    for (int hoop = 0; hoop < 2; ++hoop) {
        for (int s = wave; s < SS; s += NWAVES) {
            // ---- score pass: lane = 2t+h; 64 dims per lane ----
            const int t = lane >> 1, h = lane & 1;
            const int row = s_uti[s * TT + t];
            float acc;
            if constexpr (WM == 2) {
                const unsigned char* rp = (const unsigned char*)wtab + (long)row * DD + h * 64;
                __half2 ah0 = z2, ah1 = z2, ah2 = z2, ah3 = z2;
                #pragma unroll
                for (int j = 0; j < 4; ++j) {
                    uint4 v = *(const uint4*)(rp + 16 * j);
                    const u32* mh = &s_memh[h * 32 + 8 * j];
                    uint4 m0 = *(const uint4*)(mh);
                    uint4 m1 = *(const uint4*)(mh + 4);
                    ah0 = __hfma2(e5m2lo(v.x), u2h2(m0.x), ah0);
                    ah1 = __hfma2(e5m2hi(v.x), u2h2(m0.y), ah1);
                    ah2 = __hfma2(e5m2lo(v.y), u2h2(m0.z), ah2);
                    ah3 = __hfma2(e5m2hi(v.y), u2h2(m0.w), ah3);
                    ah0 = __hfma2(e5m2lo(v.z), u2h2(m1.x), ah0);
                    ah1 = __hfma2(e5m2hi(v.z), u2h2(m1.y), ah1);
                    ah2 = __hfma2(e5m2lo(v.w), u2h2(m1.z), ah2);
                    ah3 = __hfma2(e5m2hi(v.w), u2h2(m1.w), ah3);
                }
                __half2 ah = __hadd2(__hadd2(ah0, ah1), __hadd2(ah2, ah3));
                acc = __low2float(ah) + __high2float(ah);
            } else {
                const long base = (long)row * DD + h * 64;
                acc = 0.f;
                #pragma unroll
                for (int j = 0; j < 4; ++j) {
                    float v16[16];
                    WT<WM>::sixteen(wtab, base + 16 * j, v16);
                    const float* mp = &s_mem[h * 64 + 16 * j];
                    #pragma unroll
                    for (int k = 0; k < 16; ++k) acc += v16[k] * mp[k];
                }
            }
            acc += __shfl_xor(acc, 1, 64);   // score[t] in lanes 2t, 2t+1

            float mx = acc;
            #pragma unroll
            for (int off = 1; off < 64; off <<= 1) mx = fmaxf(mx, __shfl_xor(mx, off, 64));
            float e = expf(acc - mx);
            float sm = e;
            #pragma unroll
            for (int off = 1; off < 64; off <<= 1) sm += __shfl_xor(sm, off, 64);
            float wwt = 2.f * e / sm;        // ww[t] (duplicated per pair)

            // ---- weighted-sum: lane handles dims [4dq,4dq+4), t in its half ----
            float a0, a1, a2, a3;
            if constexpr (WM == 2) {
                const u32 wwt_u = h22u(__float2half2_rn(wwt));  // packed (wwt,wwt)
                __half2 p01 = z2, p23 = z2;
                #pragma unroll 4
                for (int i2 = 0; i2 < 16; ++i2) {
                    int t2 = th * 16 + i2;
                    __half2 wvh = u2h2((u32)__shfl((int)wwt_u, 2 * t2, 64));
                    int r2 = s_uti[s * TT + t2];
                    u32 w = *(const u32*)((const unsigned char*)wtab + (long)r2 * DD + 4 * dq);
                    p01 = __hfma2(wvh, e5m2lo(w), p01);
                    p23 = __hfma2(wvh, e5m2hi(w), p23);
                }
                a0 = __low2float(p01); a1 = __high2float(p01);
                a2 = __low2float(p23); a3 = __high2float(p23);
            } else {
                a0 = a1 = a2 = a3 = 0.f;
                #pragma unroll 4
                for (int i2 = 0; i2 < 16; ++i2) {
                    int t2 = th * 16 + i2;
                    float wv = __shfl(wwt, 2 * t2, 64);
                    int r2 = s_uti[s * TT + t2];
                    float v4[4];
                    WT<WM>::four(wtab, (long)r2 * DD + 4 * dq, v4);
                    a0 += wv * v4[0]; a1 += wv * v4[1];
                    a2 += wv * v4[2]; a3 += wv * v4[3];
                }
            }
            a0 += __shfl_xor(a0, 32, 64);
            a1 += __shfl_xor(a1, 32, 64);
            a2 += __shfl_xor(a2, 32, 64);
            a3 += __shfl_xor(a3, 32, 64);
            if (th == 0)
                *(float4*)&s_sent[s * DD + 4 * dq] = make_float4(a0, a1, a2, a3);

            // sw[s] = sentence . w_word + b_word (each dim counted twice)
            float p = a0 * ww4[0] + a1 * ww4[1] + a2 * ww4[2] + a3 * ww4[3];
            #pragma unroll
            for (int off = 1; off < 64; off <<= 1) p += __shfl_xor(p, off, 64);
            if (lane == 0) s_sw[s] = 0.5f * p + bw;
        }
        __syncthreads();

        // sentence-level softmax (wave 0)
        if (wave == 0) {
            float p = s_mem[lane] * ws0 + s_mem[lane + 64] * ws1;
            #pragma unroll
            for (int off = 1; off < 64; off <<= 1) p += __shfl_xor(p, off, 64);
            float iw = p + bs;
            float v = (lane < SS) ? tanhf(s_sw[lane] + iw) : -2.f;  // tanh in [-1,1]
            float mx = v;
            #pragma unroll
            for (int off = 1; off < 64; off <<= 1) mx = fmaxf(mx, __shfl_xor(mx, off, 64));
            float e = (lane < SS) ? expf(v - mx) : 0.f;
            float sm = e;
            #pragma unroll
            for (int off = 1; off < 64; off <<= 1) sm += __shfl_xor(sm, off, 64);
            if (lane < SS) s_swf[lane] = e / sm;
        }
        __syncthreads();

        // mem += sum_s swf[s]*sentence[s] : 6-group parallel partial sums
        {
            int g = tid >> 7;           // 0..5
            int d = tid & (DD - 1);
            float acc = 0.f;
            for (int s2 = g; s2 < SS; s2 += NGROUP)
                acc += s_swf[s2] * s_sent[s2 * DD + d];
            s_part[g * DD + d] = acc;
        }
        __syncthreads();
        if (tid < DD / 2) {
            float a0 = s_mem[2 * tid], a1 = s_mem[2 * tid + 1];
            #pragma unroll
            for (int g = 0; g < NGROUP; ++g) {
                a0 += s_part[g * DD + 2 * tid];
                a1 += s_part[g * DD + 2 * tid + 1];
            }
            s_mem[2 * tid] = a0; s_mem[2 * tid + 1] = a1;
            s_memh[tid] = h22u(__floats2half2_rn(a0, a1));
        }
        __syncthreads();
    }

    // ---------------- tail ----------------
    if (tid < LL) {
        float acc = LD<BF16>::one(b_tr, tid);
        for (int d = 0; d < DD; ++d)
            acc += s_mem[d] * LD<BF16>::one(W_tr, d * LL + tid);
        s_ept[tid] = acc;
    } else if (tid < 128) {
        int l = tid - 64;
        s_q[l] = s_item[l] * LD<BF16>::one(w_aff, l);
    } else if (tid < 128 + CLIPN) {
        s_fidx[tid - 128] = ufi[(long)u * CLIPN + (tid - 128)];
    } else if (tid >= 192 && tid < 224) {
        int j = tid - 192;
        float acc = LD<BF16>::one(b1, j);
        for (int l = 0; l < LL; ++l)
            acc += s_item[l] * LD<BF16>::one(W1, l * 32 + j);
        s_a1[j] = sigf(acc);
    }
    __syncthreads();

    const float baff = LD<BF16>::one(b_aff, 0);
    if (tid < CLIPN) {
        long fb = (long)s_fidx[tid] * LL;
        float acc = 0.f;
        for (int l = 0; l < LL; ++l) acc += LD<BF16>::one(emb_user, fb + l) * s_q[l];
        float g = sigf(acc + baff);
        s_g[tid] = g;
        LD<BF16>::st(out, NB + (long)b * CLIPN + tid, g);
    } else if (tid >= 64 && tid < 80) {
        int j = tid - 64;
        float acc = LD<BF16>::one(b2, j);
        for (int k = 0; k < 32; ++k) acc += s_a1[k] * LD<BF16>::one(W2, k * 16 + j);
        s_a2[j] = sigf(acc);
    } else if (tid == 80) {
        int cnt = 0;
        for (int c = 0; c < CLIPN; ++c) cnt += (s_fidx[c] == NFRIENDS);
        s_fnum = (float)(CLIPN - cnt);
    }
    __syncthreads();

    if (tid >= 64 && tid < 128) {
        int l = tid - 64;
        float acc = 0.f;
        for (int c = 0; c < CLIPN; ++c)
            acc += s_g[c] * LD<BF16>::one(emb_user, (long)s_fidx[c] * LL + l);
        s_uemb[l] = acc;
    } else if (tid < 2) {
        float acc = LD<BF16>::one(b3, tid);
        for (int k = 0; k < 16; ++k) acc += s_a2[k] * LD<BF16>::one(W3, k * 2 + tid);
        s_alpha[tid] = sigf(acc);
    }
    __syncthreads();

    if (wave == 0) {
        float vec = s_alpha[0] * s_ept[lane] + s_alpha[1] * (s_uemb[lane] / s_fnum);
        float p = vec * s_q[lane];
        #pragma unroll
        for (int off = 1; off < 64; off <<= 1) p += __shfl_xor(p, off, 64);
        if (lane == 0) LD<BF16>::st(out, b, sigf(p + baff));
    }
}

extern "C" void kernel_launch(void* const* d_in, const int* in_sizes, int n_in,
                              void* d_out, int out_size, void* d_ws, size_t ws_size,
                              hipStream_t stream) {
    (void)in_sizes; (void)n_in; (void)out_size;
    int* flag = (int*)d_ws;
    u32* wbuf = (u32*)((char*)d_ws + 64);
    const size_t need = 64 + (size_t)WELEMS;          // ~6.1 MiB of e5m2 bytes
    const bool ws_ok = ws_size >= need;

    sniff_dtype<<<1, 64, 0, stream>>>(d_in[2], flag);

    #define ARGS(WORDP)                                                        \
        (const int*)d_in[0], (const int*)d_in[1],                              \
        WORDP, d_in[3], d_in[4],                                               \
        d_in[5], d_in[6], d_in[7], d_in[8], d_in[9], d_in[10],                 \
        d_in[11], d_in[12], d_in[13], d_in[14], d_in[15], d_in[16],            \
        d_in[17], d_in[18], d_in[19], d_in[20],                                \
        (const int*)d_in[21], (const int*)d_in[22],                            \
        d_out, (const int*)flag

    if (ws_ok) {
        const long nthr = (WELEMS + 15) / 16;
        convert_words<<<(int)((nthr + 255) / 256), 256, 0, stream>>>(
            d_in[2], wbuf, flag);
        nrs_fused<true, 2><<<NB, NTHREADS, 0, stream>>>(ARGS((const void*)wbuf));
        nrs_fused<false, 2><<<NB, NTHREADS, 0, stream>>>(ARGS((const void*)wbuf));
    } else {
        nrs_fused<true, 1><<<NB, NTHREADS, 0, stream>>>(ARGS(d_in[2]));
        nrs_fused<false, 0><<<NB, NTHREADS, 0, stream>>>(ARGS(d_in[2]));
    }
    #undef ARGS
}